// Round 4
// baseline (106.721 us; speedup 1.0000x reference)
//
#include <hip/hip_runtime.h>

constexpr int BB = 8, TT = 2048, CC = 1024, HH = 64;
constexpr int BT = BB * TT;                         // 16384 rows total
constexpr float SC  = 0.045084220027780106f;        // (1/sqrt(1024)) * log2(e)
constexpr float NEG = -30000.0f;

typedef float  f32x4  __attribute__((ext_vector_type(4)));
typedef short  short8 __attribute__((ext_vector_type(8)));

union Frag { short8 s8; unsigned u[4]; uint4 u4; };

static __device__ inline unsigned short f2bf(float f) {        // RNE fp32->bf16
  unsigned u = __builtin_bit_cast(unsigned, f);
  u += 0x7fffu + ((u >> 16) & 1u);
  return (unsigned short)(u >> 16);
}
static __device__ inline unsigned pk2(float a, float b) {      // pack 2 bf16 (RNE)
  unsigned ua = __builtin_bit_cast(unsigned, a); ua += 0x7fffu + ((ua >> 16) & 1u);
  unsigned ub = __builtin_bit_cast(unsigned, b); ub += 0x7fffu + ((ub >> 16) & 1u);
  return (ua >> 16) | (ub & 0xffff0000u);
}
static __device__ inline unsigned pk2r(float a, float b) {     // pack, cheap round (pos values)
  unsigned ua = __builtin_bit_cast(unsigned, a) + 0x8000u;
  unsigned ub = __builtin_bit_cast(unsigned, b) + 0x8000u;
  return (ua >> 16) | (ub & 0xffff0000u);
}

// Assumed (lane-group g, slot j) -> k map used CONSISTENTLY on both MFMA input
// operands: k = 4*g + (j&3) + 16*(j>>2). Correct for any hardware k-map as
// long as A and B use identical maps (permutation consistency).
// C/D layout (HW-verified): col = lane&15, row = (lane>>4)*4 + reg.

// ---------------------------------------------------------------------------
// Kernel 0: W -> bf16, written in fragment-slot order: wt[(mat*64+n)*1024 + pos(k)]
// pos(k) = (k>>5)*32 + ((k&15)>>2)*8 + ((k>>4)&1)*4 + (k&3)
// ---------------------------------------------------------------------------
__global__ __launch_bounds__(256) void wcvt(
    const float* __restrict__ Wq, const float* __restrict__ Wk,
    const float* __restrict__ Wv, unsigned short* __restrict__ wt)
{
  const int bid = blockIdx.x;              // 0..191 = mat*64 + n
  const int mat = bid >> 6, n = bid & 63;
  const float* W = (mat == 0) ? Wq : ((mat == 1) ? Wk : Wv);
  unsigned short* o = wt + (size_t)bid * 1024;
  for (int k = threadIdx.x; k < 1024; k += 256) {
    float v = W[k * 64 + n];
    int pos = ((k >> 5) << 5) + (((k & 15) >> 2) << 3) + (((k >> 4) & 1) << 2) + (k & 3);
    o[pos] = f2bf(v);
  }
}

// ---------------------------------------------------------------------------
// Kernel 1: QKV projection via MFMA, LDS-staged x.
// grid = 512 blocks (32 rows each) x 256 thr (4 waves = 2 row-groups x 2 K-halves).
// Per K-tile (t=0..3): stage x[32 rows][2 halves x 128 cols] fp32 into LDS with
// DENSE linear global reads (each 32-lane group reads 512B contiguous) and
// XOR-swizzled ds_writes (phys_cg = cg ^ ((row&7)<<2)) so the MFMA A-fragment
// ds_read_b128s hit 8 distinct 16B slots (<=2-way bank aliasing).
// K-split partials merged through LDS (union with staging buffer).
// 32 KB LDS -> 2 blocks/CU = 8 waves/CU.
// Outputs (fragment-slot order): qb,kb row-major [row][64]; vt transposed [d][BT].
// ---------------------------------------------------------------------------
union QkvLds {
  float4 tile[2][32][32];    // [half][row][phys col-group], 32 KB
  float  pacc[2][12][64][4]; // merge scratch (kh==1 partials), 24 KB
};

__global__ __launch_bounds__(256) void qkv_proj(
    const float* __restrict__ x, const unsigned short* __restrict__ wt,
    unsigned short* __restrict__ qb, unsigned short* __restrict__ kb,
    unsigned short* __restrict__ vt)
{
  __shared__ QkvLds sm;
  const int tid = threadIdx.x, lane = tid & 63, w = tid >> 6;
  const int rg = w >> 1, kh = w & 1;
  const int l4 = lane >> 4, li = lane & 15;
  const int row0 = blockIdx.x * 32;
  const int m0 = row0 + rg * 16;

  f32x4 acc[12];
  #pragma unroll
  for (int f = 0; f < 12; ++f) acc[f] = (f32x4){0.f, 0.f, 0.f, 0.f};

  const unsigned short* wbase = wt + (size_t)li * 1024 + l4 * 8;
  const int scg = tid & 31;            // staging col-group (16B units)
  const int sr8 = tid >> 5;            // staging row-within-8

  for (int t = 0; t < 4; ++t) {
    __syncthreads();                   // WAR: previous tile's reads done
    #pragma unroll
    for (int i = 0; i < 8; ++i) {
      const int h   = i >> 2;
      const int row = ((i & 3) << 3) + sr8;
      const int phys = scg ^ ((row & 7) << 2);
      float4 v = *(const float4*)(x + (size_t)(row0 + row) * CC + h * 512 + t * 128 + scg * 4);
      sm.tile[h][row][phys] = v;
    }
    __syncthreads();                   // tile visible

    #pragma unroll
    for (int ch = 0; ch < 4; ++ch) {
      const int kb4 = ch * 8;
      const int sw = (li & 7) << 2;
      float4 fa = sm.tile[kh][rg * 16 + li][(kb4 + l4) ^ sw];
      float4 fb = sm.tile[kh][rg * 16 + li][(kb4 + 4 + l4) ^ sw];
      Frag xa;
      xa.u[0] = pk2(fa.x, fa.y); xa.u[1] = pk2(fa.z, fa.w);
      xa.u[2] = pk2(fb.x, fb.y); xa.u[3] = pk2(fb.z, fb.w);
      const int kg = kh * 512 + t * 128 + ch * 32;
      #pragma unroll
      for (int f = 0; f < 12; ++f) {
        Frag b0;
        b0.u4 = *(const uint4*)(wbase + (size_t)f * 16 * 1024 + kg);
        acc[f] = __builtin_amdgcn_mfma_f32_16x16x32_bf16(xa.s8, b0.s8, acc[f], 0, 0, 0);
      }
    }
  }

  __syncthreads();                     // tile buffer free for merge reuse
  if (kh == 1) {
    #pragma unroll
    for (int f = 0; f < 12; ++f) *(f32x4*)&sm.pacc[rg][f][lane][0] = acc[f];
  }
  __syncthreads();
  if (kh == 0) {
    #pragma unroll
    for (int f = 0; f < 12; ++f) acc[f] += *(const f32x4*)&sm.pacc[rg][f][lane][0];

    const int pc = ((li >> 2) << 3) + (li & 3);
    #pragma unroll
    for (int f = 0; f < 4; ++f) {
      const int col = ((f >> 1) << 5) + ((f & 1) << 2) + pc;
      #pragma unroll
      for (int r = 0; r < 4; ++r) {
        const size_t row = m0 + 4 * l4 + r;
        qb[row * 64 + col] = f2bf(acc[f][r]);
        kb[row * 64 + col] = f2bf(acc[4 + f][r]);
      }
    }
    const int vb = (m0 & ~31) + (((m0 >> 4) & 1) << 2) + (l4 << 3);
    #pragma unroll
    for (int f = 0; f < 4; ++f) {
      const int d = (f << 4) + li;
      unsigned lo = pk2(acc[8 + f][0], acc[8 + f][1]);
      unsigned hi = pk2(acc[8 + f][2], acc[8 + f][3]);
      *(uint2*)&vt[(size_t)d * BT + vb] = make_uint2(lo, hi);
    }
  }
}

// ---------------------------------------------------------------------------
// Kernel 2: causal flash attention, bf16 MFMA. (round-2 structure + unroll 2)
// grid = 8 batches x 32 pairs = 256 blocks, 512 thr (8 waves).
// Block handles q-groups (pr, 63-pr) [32 rows each]; wave = (16-row half, key parity).
// Swapped QK^T -> lane owns one q-row; in-register softmax; parity merge in LDS.
// ---------------------------------------------------------------------------
__global__ __launch_bounds__(512) void attn_fwd(
    const unsigned short* __restrict__ qb, const unsigned short* __restrict__ kb,
    const unsigned short* __restrict__ vt, float* __restrict__ out)
{
  __shared__ float oacc[8][16][64];        // 32 KB
  __shared__ float ml[8][2][16];
  const int tid = threadIdx.x, lane = tid & 63, w = tid >> 6;
  const int par = w & 1, qgh = w >> 1;
  const int pr = blockIdx.x & 31, b = blockIdx.x >> 5;
  const int g32 = (qgh < 2) ? pr : 63 - pr;
  const int q0 = g32 * 32 + (qgh & 1) * 16;           // within batch
  const int ktmax = q0 >> 5;
  const int bT = b * TT;
  const int l4 = lane >> 4, li = lane & 15;
  const int qrow = q0 + li;

  Frag qf0, qf1;
  {
    const unsigned short* qp = qb + (size_t)(bT + q0 + li) * 64 + l4 * 8;
    qf0.u4 = *(const uint4*)(qp);
    qf1.u4 = *(const uint4*)(qp + 32);
  }

  f32x4 acc0 = {0,0,0,0}, acc1 = {0,0,0,0}, acc2 = {0,0,0,0}, acc3 = {0,0,0,0};
  float mreg = NEG, lsum = 0.f;

  #pragma unroll 2
  for (int kt = par; kt <= ktmax; kt += 2) {
    const int key0 = kt * 32;
    const unsigned short* kp = kb + (size_t)(bT + key0 + li) * 64 + l4 * 8;
    Frag k00, k01, k10, k11;
    k00.u4 = *(const uint4*)(kp);
    k01.u4 = *(const uint4*)(kp + 32);
    k10.u4 = *(const uint4*)(kp + 16 * 64);
    k11.u4 = *(const uint4*)(kp + 16 * 64 + 32);
    const unsigned short* vp = vt + (size_t)li * BT + bT + key0 + l4 * 8;
    Frag v0, v1, v2, v3;
    v0.u4 = *(const uint4*)(vp);
    v1.u4 = *(const uint4*)(vp + (size_t)16 * BT);
    v2.u4 = *(const uint4*)(vp + (size_t)32 * BT);
    v3.u4 = *(const uint4*)(vp + (size_t)48 * BT);

    f32x4 s0 = {0,0,0,0}, s1 = {0,0,0,0};
    s0 = __builtin_amdgcn_mfma_f32_16x16x32_bf16(k00.s8, qf0.s8, s0, 0, 0, 0);
    s0 = __builtin_amdgcn_mfma_f32_16x16x32_bf16(k01.s8, qf1.s8, s0, 0, 0, 0);
    s1 = __builtin_amdgcn_mfma_f32_16x16x32_bf16(k10.s8, qf0.s8, s1, 0, 0, 0);
    s1 = __builtin_amdgcn_mfma_f32_16x16x32_bf16(k11.s8, qf1.s8, s1, 0, 0, 0);

    float sv[8];
    float pm = NEG;
    #pragma unroll
    for (int r = 0; r < 4; ++r) {
      const int kA = key0 + 4 * l4 + r;
      float a = s0[r] * SC; a = (kA       <= qrow) ? a : NEG;
      float c = s1[r] * SC; c = (kA + 16  <= qrow) ? c : NEG;
      sv[r] = a; sv[r + 4] = c;
      pm = fmaxf(pm, fmaxf(a, c));
    }
    pm = fmaxf(pm, __shfl_xor(pm, 16));
    pm = fmaxf(pm, __shfl_xor(pm, 32));

    if (__any(pm > mreg + 8.0f)) {                     // defer-max rescale
      const float mnew = fmaxf(mreg, pm);
      const float corr = exp2f(mreg - mnew);
      lsum *= corr;
      #pragma unroll
      for (int r = 0; r < 4; ++r) {
        const float cr = __shfl(corr, 4 * l4 + r);
        acc0[r] *= cr; acc1[r] *= cr; acc2[r] *= cr; acc3[r] *= cr;
      }
      mreg = mnew;
    }

    float p[8], psum = 0.f;
    #pragma unroll
    for (int j = 0; j < 8; ++j) { p[j] = exp2f(sv[j] - mreg); psum += p[j]; }
    psum += __shfl_xor(psum, 16);
    psum += __shfl_xor(psum, 32);
    lsum += psum;

    Frag pf;
    pf.u[0] = pk2r(p[0], p[1]); pf.u[1] = pk2r(p[2], p[3]);
    pf.u[2] = pk2r(p[4], p[5]); pf.u[3] = pk2r(p[6], p[7]);

    acc0 = __builtin_amdgcn_mfma_f32_16x16x32_bf16(pf.s8, v0.s8, acc0, 0, 0, 0);
    acc1 = __builtin_amdgcn_mfma_f32_16x16x32_bf16(pf.s8, v1.s8, acc1, 0, 0, 0);
    acc2 = __builtin_amdgcn_mfma_f32_16x16x32_bf16(pf.s8, v2.s8, acc2, 0, 0, 0);
    acc3 = __builtin_amdgcn_mfma_f32_16x16x32_bf16(pf.s8, v3.s8, acc3, 0, 0, 0);
  }

  // ---- merge parity-partner waves ----
  if (par == 1) {
    #pragma unroll
    for (int r = 0; r < 4; ++r) {
      const int row = 4 * l4 + r;
      oacc[w][row][li]      = acc0[r];
      oacc[w][row][16 + li] = acc1[r];
      oacc[w][row][32 + li] = acc2[r];
      oacc[w][row][48 + li] = acc3[r];
    }
    if (l4 == 0) { ml[w][0][li] = mreg; ml[w][1][li] = lsum; }
  }
  __syncthreads();
  if (par == 0) {
    const float m1 = ml[w + 1][0][li], l1 = ml[w + 1][1][li];
    const float ms = fmaxf(mreg, m1);
    float a0 = exp2f(mreg - ms), a1 = exp2f(m1 - ms);
    const float L = lsum * a0 + l1 * a1;
    const float inv = 1.0f / L;
    a0 *= inv; a1 *= inv;
    float* op = out + (size_t)(bT + q0) * 64;
    #pragma unroll
    for (int r = 0; r < 4; ++r) {
      const float w0 = __shfl(a0, 4 * l4 + r);
      const float w1 = __shfl(a1, 4 * l4 + r);
      const int row = 4 * l4 + r;
      op[row * 64 + li]      = acc0[r] * w0 + oacc[w + 1][row][li]      * w1;
      op[row * 64 + 16 + li] = acc1[r] * w0 + oacc[w + 1][row][16 + li] * w1;
      op[row * 64 + 32 + li] = acc2[r] * w0 + oacc[w + 1][row][32 + li] * w1;
      op[row * 64 + 48 + li] = acc3[r] * w0 + oacc[w + 1][row][48 + li] * w1;
    }
  }
}

// ---------------------------------------------------------------------------
extern "C" void kernel_launch(void* const* d_in, const int* in_sizes, int n_in,
                              void* d_out, int out_size, void* d_ws, size_t ws_size,
                              hipStream_t stream) {
  const float* x  = (const float*)d_in[0];
  const float* Wq = (const float*)d_in[1];
  const float* Wk = (const float*)d_in[2];
  const float* Wv = (const float*)d_in[3];
  float* outp = (float*)d_out;

  unsigned short* wt = (unsigned short*)d_ws;        // [3*64][1024]  = 196608
  unsigned short* qb = wt + 196608;                  // [BT][64]
  unsigned short* kb = qb + (size_t)BT * 64;         // [BT][64]
  unsigned short* vt = kb + (size_t)BT * 64;         // [64][BT]

  wcvt<<<192, 256, 0, stream>>>(Wq, Wk, Wv, wt);
  qkv_proj<<<512, 256, 0, stream>>>(x, wt, qb, kb, vt);
  attn_fwd<<<256, 512, 0, stream>>>(qb, kb, vt, outp);
}

// Round 5
// 70.294 us; speedup vs baseline: 1.5182x; 1.5182x over previous
//
#include <hip/hip_runtime.h>

constexpr int BB = 8, TT = 2048, CC = 1024, HH = 64;
constexpr int BT = BB * TT;                         // 16384 rows total
constexpr float SC  = 0.045084220027780106f;        // (1/sqrt(1024)) * log2(e)
constexpr float NEG = -30000.0f;

typedef float  f32x4  __attribute__((ext_vector_type(4)));
typedef short  short8 __attribute__((ext_vector_type(8)));

union Frag { short8 s8; unsigned u[4]; uint4 u4; };

static __device__ inline unsigned short f2bf(float f) {        // RNE fp32->bf16
  unsigned u = __builtin_bit_cast(unsigned, f);
  u += 0x7fffu + ((u >> 16) & 1u);
  return (unsigned short)(u >> 16);
}
static __device__ inline unsigned pk2(float a, float b) {      // pack 2 bf16 (RNE)
  unsigned ua = __builtin_bit_cast(unsigned, a); ua += 0x7fffu + ((ua >> 16) & 1u);
  unsigned ub = __builtin_bit_cast(unsigned, b); ub += 0x7fffu + ((ub >> 16) & 1u);
  return (ua >> 16) | (ub & 0xffff0000u);
}
static __device__ inline unsigned pk2r(float a, float b) {     // pack, cheap round (pos values)
  unsigned ua = __builtin_bit_cast(unsigned, a) + 0x8000u;
  unsigned ub = __builtin_bit_cast(unsigned, b) + 0x8000u;
  return (ua >> 16) | (ub & 0xffff0000u);
}

// Fragment slot map (both MFMA operands, used consistently everywhere):
// slot s of lane-group l4 covers k = 4*l4 + (s&3) + 16*(s>>2); within a
// 32-k block the storage position is p = l4*8 + s (pos32(k) =
// ((k&15)>>2)*8 + ((k>>4)&1)*4 + (k&3)).
// C/D layout (HW-verified): col = lane&15, row = (lane>>4)*4 + reg.

// ---------------------------------------------------------------------------
// Kernel 0: W -> bf16 in wave-contiguous fragment order:
// wt[fg][kf][li][l4*8+s] with fg = mat*4 + (n>>4), li = n&15.
// One B-frag load in qkv_proj = 64 lanes x 16B = 1KB dense.
// ---------------------------------------------------------------------------
__global__ __launch_bounds__(256) void wcvt(
    const float* __restrict__ Wq, const float* __restrict__ Wk,
    const float* __restrict__ Wv, unsigned short* __restrict__ wt)
{
  const int bid = blockIdx.x;              // 0..191 = mat*64 + n
  const int mat = bid >> 6, n = bid & 63;
  const float* W = (mat == 0) ? Wq : ((mat == 1) ? Wk : Wv);
  unsigned short* o = wt + ((size_t)(mat * 4 + (n >> 4)) * 32) * 512 + (n & 15) * 32;
  for (int k = threadIdx.x; k < 1024; k += 256) {
    const int p = (((k & 15) >> 2) << 3) + (((k >> 4) & 1) << 2) + (k & 3);
    o[(size_t)(k >> 5) * 512 + p] = f2bf(W[k * 64 + n]);
  }
}

// ---------------------------------------------------------------------------
// Kernel 1: QKV projection via MFMA, fully wave-coalesced.
// grid = 256 blocks (64 rows each) x 256 thr (4 waves).
// Wave w owns col-groups fg = 3w..3w+2 (16 cols each) for ALL 64 rows, full K
// -> no partial-sum merge; W read once per block (384 KB = all of W).
// x staged bf16 in LDS (double-buffered K-256 tiles), stage loads for t+1
// issued before compute of t (T14). Every global load and ds_read_b128 in the
// hot loop is a dense 1KB wave access.
// ---------------------------------------------------------------------------
__global__ __launch_bounds__(256) void qkv_proj(
    const float* __restrict__ x, const unsigned short* __restrict__ wt,
    unsigned short* __restrict__ qb, unsigned short* __restrict__ kb,
    unsigned short* __restrict__ vt)
{
  __shared__ unsigned short xt[2][4][8][16][32];  // [buf][rq][kf][li][l4*8+s], 64 KB
  const int tid = threadIdx.x, lane = tid & 63, w = tid >> 6;
  const int li = lane & 15, l4 = lane >> 4;
  const int row0 = blockIdx.x * 64;

  f32x4 acc[3][4];
  #pragma unroll
  for (int j = 0; j < 3; ++j)
    #pragma unroll
    for (int rq = 0; rq < 4; ++rq) acc[j][rq] = (f32x4){0.f, 0.f, 0.f, 0.f};

  // staging: wave w stages rows w*16..w*16+15; lane covers float4 #lane of the
  // 256-col slice (k-offset lane*4): kf = lane>>3, slot offset g*8+h*4.
  const int skf  = lane >> 3;
  const int soff = (lane & 3) * 8 + ((lane >> 2) & 1) * 4;
  const float* xrow = x + (size_t)(row0 + w * 16) * CC + (lane << 2);

  float4 sr[16];
  #pragma unroll
  for (int ir = 0; ir < 16; ++ir) sr[ir] = *(const float4*)(xrow + (size_t)ir * CC);

  for (int t = 0; t < 4; ++t) {
    unsigned short* dst = &xt[t & 1][w][skf][0][0] + soff;
    #pragma unroll
    for (int ir = 0; ir < 16; ++ir) {
      uint2 pv = make_uint2(pk2(sr[ir].x, sr[ir].y), pk2(sr[ir].z, sr[ir].w));
      *(uint2*)(dst + ir * 32) = pv;
    }
    __syncthreads();                       // tile t visible
    if (t < 3) {                           // issue next stage early (T14)
      const float* xn = xrow + (t + 1) * 256;
      #pragma unroll
      for (int ir = 0; ir < 16; ++ir) sr[ir] = *(const float4*)(xn + (size_t)ir * CC);
    }
    #pragma unroll
    for (int half = 0; half < 2; ++half) {
      Frag b[3][4];
      #pragma unroll
      for (int kk = 0; kk < 4; ++kk) {
        const int kf = half * 4 + kk;
        #pragma unroll
        for (int j = 0; j < 3; ++j) {
          const int fg = 3 * w + j;
          b[j][kk].u4 = *(const uint4*)(wt + ((size_t)fg * 32 + t * 8 + kf) * 512
                                           + li * 32 + l4 * 8);
        }
      }
      #pragma unroll
      for (int kk = 0; kk < 4; ++kk) {
        const int kf = half * 4 + kk;
        Frag a[4];
        #pragma unroll
        for (int rq = 0; rq < 4; ++rq)
          a[rq].u4 = *(const uint4*)(&xt[t & 1][rq][kf][li][0] + l4 * 8);
        #pragma unroll
        for (int j = 0; j < 3; ++j)
          #pragma unroll
          for (int rq = 0; rq < 4; ++rq)
            acc[j][rq] = __builtin_amdgcn_mfma_f32_16x16x32_bf16(
                a[rq].s8, b[j][kk].s8, acc[j][rq], 0, 0, 0);
      }
    }
    __syncthreads();                       // all waves done with buf before reuse
  }

  // stores: wave-uniform mat branches; q/k row-major, v transposed+pos32 order
  #pragma unroll
  for (int j = 0; j < 3; ++j) {
    const int fg = 3 * w + j, mat = fg >> 2, fi = fg & 3;
    if (mat < 2) {
      unsigned short* o = (mat == 0) ? qb : kb;
      #pragma unroll
      for (int rq = 0; rq < 4; ++rq)
        #pragma unroll
        for (int r = 0; r < 4; ++r) {
          const size_t row = row0 + rq * 16 + l4 * 4 + r;
          o[row * 64 + fi * 16 + li] = f2bf(acc[j][rq][r]);
        }
    } else {
      const int d = fi * 16 + li;
      #pragma unroll
      for (int rq = 0; rq < 4; ++rq) {
        const int base32 = row0 + (rq >> 1) * 32;
        const int pos = l4 * 8 + (rq & 1) * 4;
        uint2 pv = make_uint2(pk2(acc[j][rq][0], acc[j][rq][1]),
                              pk2(acc[j][rq][2], acc[j][rq][3]));
        *(uint2*)&vt[(size_t)d * BT + base32 + pos] = pv;
      }
    }
  }
}

// ---------------------------------------------------------------------------
// Kernel 2: causal flash attention, bf16 MFMA. (unchanged)
// grid = 8 batches x 32 pairs = 256 blocks, 512 thr (8 waves).
// Block handles q-groups (pr, 63-pr) [32 rows each]; wave = (16-row half, key parity).
// Swapped QK^T -> lane owns one q-row; in-register softmax; parity merge in LDS.
// ---------------------------------------------------------------------------
__global__ __launch_bounds__(512) void attn_fwd(
    const unsigned short* __restrict__ qb, const unsigned short* __restrict__ kb,
    const unsigned short* __restrict__ vt, float* __restrict__ out)
{
  __shared__ float oacc[8][16][64];        // 32 KB
  __shared__ float ml[8][2][16];
  const int tid = threadIdx.x, lane = tid & 63, w = tid >> 6;
  const int par = w & 1, qgh = w >> 1;
  const int pr = blockIdx.x & 31, b = blockIdx.x >> 5;
  const int g32 = (qgh < 2) ? pr : 63 - pr;
  const int q0 = g32 * 32 + (qgh & 1) * 16;           // within batch
  const int ktmax = q0 >> 5;
  const int bT = b * TT;
  const int l4 = lane >> 4, li = lane & 15;
  const int qrow = q0 + li;

  Frag qf0, qf1;
  {
    const unsigned short* qp = qb + (size_t)(bT + q0 + li) * 64 + l4 * 8;
    qf0.u4 = *(const uint4*)(qp);
    qf1.u4 = *(const uint4*)(qp + 32);
  }

  f32x4 acc0 = {0,0,0,0}, acc1 = {0,0,0,0}, acc2 = {0,0,0,0}, acc3 = {0,0,0,0};
  float mreg = NEG, lsum = 0.f;

  #pragma unroll 2
  for (int kt = par; kt <= ktmax; kt += 2) {
    const int key0 = kt * 32;
    const unsigned short* kp = kb + (size_t)(bT + key0 + li) * 64 + l4 * 8;
    Frag k00, k01, k10, k11;
    k00.u4 = *(const uint4*)(kp);
    k01.u4 = *(const uint4*)(kp + 32);
    k10.u4 = *(const uint4*)(kp + 16 * 64);
    k11.u4 = *(const uint4*)(kp + 16 * 64 + 32);
    const unsigned short* vp = vt + (size_t)li * BT + bT + key0 + l4 * 8;
    Frag v0, v1, v2, v3;
    v0.u4 = *(const uint4*)(vp);
    v1.u4 = *(const uint4*)(vp + (size_t)16 * BT);
    v2.u4 = *(const uint4*)(vp + (size_t)32 * BT);
    v3.u4 = *(const uint4*)(vp + (size_t)48 * BT);

    f32x4 s0 = {0,0,0,0}, s1 = {0,0,0,0};
    s0 = __builtin_amdgcn_mfma_f32_16x16x32_bf16(k00.s8, qf0.s8, s0, 0, 0, 0);
    s0 = __builtin_amdgcn_mfma_f32_16x16x32_bf16(k01.s8, qf1.s8, s0, 0, 0, 0);
    s1 = __builtin_amdgcn_mfma_f32_16x16x32_bf16(k10.s8, qf0.s8, s1, 0, 0, 0);
    s1 = __builtin_amdgcn_mfma_f32_16x16x32_bf16(k11.s8, qf1.s8, s1, 0, 0, 0);

    float sv[8];
    float pm = NEG;
    #pragma unroll
    for (int r = 0; r < 4; ++r) {
      const int kA = key0 + 4 * l4 + r;
      float a = s0[r] * SC; a = (kA       <= qrow) ? a : NEG;
      float c = s1[r] * SC; c = (kA + 16  <= qrow) ? c : NEG;
      sv[r] = a; sv[r + 4] = c;
      pm = fmaxf(pm, fmaxf(a, c));
    }
    pm = fmaxf(pm, __shfl_xor(pm, 16));
    pm = fmaxf(pm, __shfl_xor(pm, 32));

    if (__any(pm > mreg + 8.0f)) {                     // defer-max rescale
      const float mnew = fmaxf(mreg, pm);
      const float corr = exp2f(mreg - mnew);
      lsum *= corr;
      #pragma unroll
      for (int r = 0; r < 4; ++r) {
        const float cr = __shfl(corr, 4 * l4 + r);
        acc0[r] *= cr; acc1[r] *= cr; acc2[r] *= cr; acc3[r] *= cr;
      }
      mreg = mnew;
    }

    float p[8], psum = 0.f;
    #pragma unroll
    for (int j = 0; j < 8; ++j) { p[j] = exp2f(sv[j] - mreg); psum += p[j]; }
    psum += __shfl_xor(psum, 16);
    psum += __shfl_xor(psum, 32);
    lsum += psum;

    Frag pf;
    pf.u[0] = pk2r(p[0], p[1]); pf.u[1] = pk2r(p[2], p[3]);
    pf.u[2] = pk2r(p[4], p[5]); pf.u[3] = pk2r(p[6], p[7]);

    acc0 = __builtin_amdgcn_mfma_f32_16x16x32_bf16(pf.s8, v0.s8, acc0, 0, 0, 0);
    acc1 = __builtin_amdgcn_mfma_f32_16x16x32_bf16(pf.s8, v1.s8, acc1, 0, 0, 0);
    acc2 = __builtin_amdgcn_mfma_f32_16x16x32_bf16(pf.s8, v2.s8, acc2, 0, 0, 0);
    acc3 = __builtin_amdgcn_mfma_f32_16x16x32_bf16(pf.s8, v3.s8, acc3, 0, 0, 0);
  }

  // ---- merge parity-partner waves ----
  if (par == 1) {
    #pragma unroll
    for (int r = 0; r < 4; ++r) {
      const int row = 4 * l4 + r;
      oacc[w][row][li]      = acc0[r];
      oacc[w][row][16 + li] = acc1[r];
      oacc[w][row][32 + li] = acc2[r];
      oacc[w][row][48 + li] = acc3[r];
    }
    if (l4 == 0) { ml[w][0][li] = mreg; ml[w][1][li] = lsum; }
  }
  __syncthreads();
  if (par == 0) {
    const float m1 = ml[w + 1][0][li], l1 = ml[w + 1][1][li];
    const float ms = fmaxf(mreg, m1);
    float a0 = exp2f(mreg - ms), a1 = exp2f(m1 - ms);
    const float L = lsum * a0 + l1 * a1;
    const float inv = 1.0f / L;
    a0 *= inv; a1 *= inv;
    float* op = out + (size_t)(bT + q0) * 64;
    #pragma unroll
    for (int r = 0; r < 4; ++r) {
      const float w0 = __shfl(a0, 4 * l4 + r);
      const float w1 = __shfl(a1, 4 * l4 + r);
      const int row = 4 * l4 + r;
      op[row * 64 + li]      = acc0[r] * w0 + oacc[w + 1][row][li]      * w1;
      op[row * 64 + 16 + li] = acc1[r] * w0 + oacc[w + 1][row][16 + li] * w1;
      op[row * 64 + 32 + li] = acc2[r] * w0 + oacc[w + 1][row][32 + li] * w1;
      op[row * 64 + 48 + li] = acc3[r] * w0 + oacc[w + 1][row][48 + li] * w1;
    }
  }
}

// ---------------------------------------------------------------------------
extern "C" void kernel_launch(void* const* d_in, const int* in_sizes, int n_in,
                              void* d_out, int out_size, void* d_ws, size_t ws_size,
                              hipStream_t stream) {
  const float* x  = (const float*)d_in[0];
  const float* Wq = (const float*)d_in[1];
  const float* Wk = (const float*)d_in[2];
  const float* Wv = (const float*)d_in[3];
  float* outp = (float*)d_out;

  unsigned short* wt = (unsigned short*)d_ws;        // [12][32][16][32] = 196608
  unsigned short* qb = wt + 196608;                  // [BT][64]
  unsigned short* kb = qb + (size_t)BT * 64;         // [BT][64]
  unsigned short* vt = kb + (size_t)BT * 64;         // [64][BT]

  wcvt<<<192, 256, 0, stream>>>(Wq, Wk, Wv, wt);
  qkv_proj<<<256, 256, 0, stream>>>(x, wt, qb, kb, vt);
  attn_fwd<<<256, 512, 0, stream>>>(qb, kb, vt, outp);
}